// Round 18
// baseline (128.480 us; speedup 1.0000x reference)
//
#include <hip/hip_runtime.h>
#include <hip/hip_bf16.h>

#define DEV __device__ __forceinline__

typedef __bf16 bf16x8 __attribute__((ext_vector_type(8)));
typedef float  f32x4  __attribute__((ext_vector_type(4)));

typedef __attribute__((address_space(3))) unsigned int LDSU;
typedef __attribute__((address_space(1))) const unsigned int GLBU;

DEV unsigned short f2b(float f){
  __bf16 h = (__bf16)f;
  return __builtin_bit_cast(unsigned short, h);
}

static constexpr float MAXLOG = 4.60517018598809136804f;  // log(100)
static constexpr float L2E    = 1.44269504088896340736f;  // log2(e)

// ---------------- fused fp32 -> bf16 convert: x | W_qkv | W_proj ----------------
DEV ushort4 cvt4(float4 v){
  ushort4 o; o.x = f2b(v.x); o.y = f2b(v.y); o.z = f2b(v.z); o.w = f2b(v.w); return o;
}
__global__ void cvt3_kernel(const float4* __restrict__ a, ushort4* __restrict__ da, int na,
                            const float4* __restrict__ b, ushort4* __restrict__ db, int nb,
                            const float4* __restrict__ c, ushort4* __restrict__ dc, int nc){
  int i = blockIdx.x * 256 + threadIdx.x;
  if (i < na) { da[i] = cvt4(a[i]); return; }
  i -= na;
  if (i < nb) { db[i] = cvt4(b[i]); return; }
  i -= nb;
  if (i < nc) { dc[i] = cvt4(c[i]); }
}

// ---------------- QKV GEMM + bias + L2norm/scale epilogue ----------------
// (R13/R15 structure — green) BM=128, BN=128, BK=64, 512 thr / 8 waves, dbuf.
// CHANGE vs R17: q additionally scaled by log2(e) so attn can use exp2 directly.
__global__ __launch_bounds__(512) void qkv_gemm(
    const unsigned short* __restrict__ X,
    const unsigned short* __restrict__ W,
    const float* __restrict__ qbias, const float* __restrict__ vbias,
    const float* __restrict__ lsm,
    unsigned short* __restrict__ Qo, unsigned short* __restrict__ Ko,
    unsigned short* __restrict__ Vo)
{
  __shared__ char smem[65536];   // A dbuf 2x16K @0 | B dbuf 2x16K @32768
  const int tid = threadIdx.x;
  const int l = tid & 63, w = tid >> 6;   // 8 waves
  const int wr = w >> 1, wc = w & 1;      // 4 x 2 wave grid
  const int lr = l & 15, lg = l >> 4;
  const int tm = blockIdx.x % 64;
  const int tn = blockIdx.x / 64;         // 0..17
  const int m0 = tm * 128, n0 = tn * 128;

  f32x4 acc[2][4];
  #pragma unroll
  for (int i=0;i<2;i++)
    #pragma unroll
    for (int j=0;j<4;j++) acc[i][j] = (f32x4){0.f,0.f,0.f,0.f};

  #pragma unroll
  for (int c=0;c<2;++c){
    int chunk = c*512 + tid;
    int row = chunk >> 3;
    int scc = (chunk & 7) ^ (row & 7);    // inverse-swizzled source chunk
    __builtin_amdgcn_global_load_lds((GLBU*)(X + (size_t)(m0+row)*768 + scc*8),
                                     (LDSU*)(smem + chunk*16), 16, 0, 0);
    __builtin_amdgcn_global_load_lds((GLBU*)(W + (size_t)(n0+row)*768 + scc*8),
                                     (LDSU*)(smem + 32768 + chunk*16), 16, 0, 0);
  }

  for (int kt = 0; kt < 12; ++kt){
    __syncthreads();                      // parity (kt&1) staged & visible
    const int pc = kt & 1;
    char* Acur = smem + pc*16384;
    char* Bcur = smem + 32768 + pc*16384;

    if (kt + 1 < 12){                     // stage-early next K-tile (no waits)
      const int k1 = (kt+1)*64;
      char* Anxt = smem + (pc^1)*16384;
      char* Bnxt = smem + 32768 + (pc^1)*16384;
      #pragma unroll
      for (int c=0;c<2;++c){
        int chunk = c*512 + tid;
        int row = chunk >> 3;
        int scc = (chunk & 7) ^ (row & 7);
        __builtin_amdgcn_global_load_lds((GLBU*)(X + (size_t)(m0+row)*768 + k1 + scc*8),
                                         (LDSU*)(Anxt + chunk*16), 16, 0, 0);
        __builtin_amdgcn_global_load_lds((GLBU*)(W + (size_t)(n0+row)*768 + k1 + scc*8),
                                         (LDSU*)(Bnxt + chunk*16), 16, 0, 0);
      }
    }

    #pragma unroll
    for (int kk = 0; kk < 2; ++kk){
      bf16x8 af[2], bfv[4];
      #pragma unroll
      for (int m=0;m<2;m++){
        int row = wr*32 + m*16 + lr;
        int byte = kk*64 + lg*16;
        af[m] = *(const bf16x8*)(Acur + row*128 + (byte ^ ((row&7)<<4)));
      }
      #pragma unroll
      for (int n=0;n<4;n++){
        int row = wc*64 + n*16 + lr;
        int byte = kk*64 + lg*16;
        bfv[n] = *(const bf16x8*)(Bcur + row*128 + (byte ^ ((row&7)<<4)));
      }
      #pragma unroll
      for (int m=0;m<2;m++)
        #pragma unroll
        for (int n=0;n<4;n++)
          acc[m][n] = __builtin_amdgcn_mfma_f32_16x16x32_bf16(af[m], bfv[n], acc[m][n], 0, 0, 0);
    }
  }

  const int nb = n0 + wc*64;
  const int seg = nb / 768;             // 0=q, 1=k, 2=v
  const int h = (nb % 768) / 64;
  float mul = 1.0f;
  if (seg == 0) mul = __expf(fminf(lsm[h], MAXLOG)) * L2E;   // fold log2e into q
  float bias_v[4];
  #pragma unroll
  for (int n=0;n<4;n++){
    int d = n*16 + lr;
    bias_v[n] = (seg==0) ? qbias[h*64+d] : (seg==2 ? vbias[h*64+d] : 0.f);
  }
  unsigned short* dst = (seg==0) ? Qo : (seg==1 ? Ko : Vo);
  #pragma unroll
  for (int m=0;m<2;m++){
    #pragma unroll
    for (int r=0;r<4;r++){
      float vals[4]; float ss = 0.f;
      #pragma unroll
      for (int n=0;n<4;n++){ float v = acc[m][n][r] + bias_v[n]; vals[n] = v; ss += v*v; }
      ss += __shfl_xor(ss,1); ss += __shfl_xor(ss,2);
      ss += __shfl_xor(ss,4); ss += __shfl_xor(ss,8);
      float sc = (seg==2) ? 1.f : mul / fmaxf(sqrtf(ss), 1e-12f);
      int grow = m0 + wr*32 + m*16 + lg*4 + r;   // 0..8191
      int b = grow >> 11, lrow = grow & 2047;
      size_t base = (((size_t)(b*12 + h))*2048 + lrow)*64;
      #pragma unroll
      for (int n=0;n<4;n++) dst[base + n*16 + lr] = f2b(vals[n]*sc);
    }
  }
}

// ---------------- block-causal flash attention (8 waves, 16 q-rows/wave) ----------------
// (R15/R17 structure — green). CHANGES: softmax in log2 domain (q carries the
// log2e factor -> exp2f, no per-value mul) + u32-pair P packing (bit-identical
// stores, fewer VALU ops than u64 shift/or chain).
__global__ __launch_bounds__(512) void attn_kernel(
    const unsigned short* __restrict__ Q,
    const unsigned short* __restrict__ K,
    const unsigned short* __restrict__ V,
    const float* __restrict__ lsm,
    unsigned short* __restrict__ O)
{
  __shared__ char smem[49152];     // K dbuf 16K | V dbuf 16K | P 8x2K
  const int tid = threadIdx.x;
  const int l = tid & 63, w = tid >> 6;          // 8 waves
  char* Plds = smem + 32768 + w*2048;            // per-wave [16 q][64 key] bf16, swizzled
  const int lr = l & 15, lg = l >> 4;

  const int bid = blockIdx.x;
  const int qb = 15 - (bid / 48);        // heaviest q-blocks first (LPT)
  const int bh = bid % 48;
  const int h = bh % 12;
  const size_t plane = (size_t)bh * (2048*64);
  const int q0 = qb*128 + w*16;          // 16 q-rows per wave

  // fixed softmax shift in log2 domain (q carries log2e: S = L2E * smul * cos)
  const float M = __expf(fminf(lsm[h], MAXLOG)) * L2E;

  bf16x8 qf[2];
  #pragma unroll
  for (int ki=0;ki<2;ki++)
    qf[ki] = *(const bf16x8*)(Q + plane + (size_t)(q0 + lr)*64 + ki*32 + lg*8);

  float lsum = 0.f;
  f32x4 of[4];
  #pragma unroll
  for (int di=0;di<4;di++) of[di] = (f32x4){0.f,0.f,0.f,0.f};

  const int krow = tid >> 3;                 // 0..63
  const int kscc = (tid & 7) ^ (krow & 7);   // K inverse-swizzled source chunk
  const int rv  = tid & 63;                  // V row (per-wave: all 64 rows)
  const int c0v = (tid >> 6) * 8;            // V d-chunk (per-wave constant)

  const int nt = (qb + 1) * 2;     // visible 64-key tiles (block-causal, BLOCK=128)

  {
    const unsigned short* Kt0 = K + plane;
    const unsigned short* Vt0 = V + plane;
    __builtin_amdgcn_global_load_lds((GLBU*)(Kt0 + krow*64 + kscc*8),
                                     (LDSU*)(smem + tid*16), 16, 0, 0);
    bf16x8 a = *(const bf16x8*)(Vt0 + rv*64 + c0v);
    #pragma unroll
    for (int j=0;j<8;j++)
      *(__bf16*)(smem + 16384 + (c0v+j)*128 + ((2*rv) ^ (j<<4))) = a[j];
  }

  for (int t = 0; t < nt; ++t){
    __syncthreads();
    const int pc = t & 1;
    char* Kcur = smem + pc*8192;
    char* Vcur = smem + 16384 + pc*8192;
    char* Knxt = smem + (pc^1)*8192;
    char* Vnxt = smem + 16384 + (pc^1)*8192;
    const bool pre = (t+1) < nt;

    bf16x8 nv;
    if (pre){
      const unsigned short* Kt1 = K + plane + (size_t)(t+1)*4096;
      const unsigned short* Vt1 = V + plane + (size_t)(t+1)*4096;
      __builtin_amdgcn_global_load_lds((GLBU*)(Kt1 + krow*64 + kscc*8),
                                       (LDSU*)(Knxt + tid*16), 16, 0, 0);
      nv = *(const bf16x8*)(Vt1 + rv*64 + c0v);
    }

    f32x4 s[4];
    #pragma unroll
    for (int ni=0;ni<4;ni++) s[ni] = (f32x4){0.f,0.f,0.f,0.f};
    #pragma unroll
    for (int ki=0;ki<2;ki++){
      bf16x8 kb[4];
      #pragma unroll
      for (int ni=0;ni<4;ni++){
        int key = ni*16 + lr;
        int byte = ki*64 + lg*16;
        kb[ni] = *(const bf16x8*)(Kcur + key*128 + (byte ^ ((key&7)<<4)));
      }
      __builtin_amdgcn_s_setprio(1);
      #pragma unroll
      for (int ni=0;ni<4;ni++)
        s[ni] = __builtin_amdgcn_mfma_f32_16x16x32_bf16(kb[ni], qf[ki], s[ni], 0, 0, 0);
      __builtin_amdgcn_s_setprio(0);
    }

    // fixed-max softmax in log2 domain; u32-pair packed b64 P-writes
    {
      const int row = lr;
      float a16 = 0.f;
      #pragma unroll
      for (int ni=0;ni<4;ni++){
        float p0 = exp2f(s[ni][0] - M);
        float p1 = exp2f(s[ni][1] - M);
        float p2 = exp2f(s[ni][2] - M);
        float p3 = exp2f(s[ni][3] - M);
        a16 += (p0 + p1) + (p2 + p3);
        uint2 uv;
        uv.x = (unsigned)f2b(p0) | ((unsigned)f2b(p1) << 16);
        uv.y = (unsigned)f2b(p2) | ((unsigned)f2b(p3) << 16);
        *(uint2*)(Plds + row*128 + ((ni*32 + lg*8) ^ ((row&7)<<4))) = uv;
      }
      lsum += a16;
    }
    asm volatile("s_waitcnt lgkmcnt(0)" ::: "memory");
    __builtin_amdgcn_sched_barrier(0);

    #pragma unroll
    for (int ki=0;ki<2;ki++){
      bf16x8 pa, vbf[4];
      {
        int row = lr;
        int byte = ki*64 + lg*16;
        pa = *(const bf16x8*)(Plds + row*128 + (byte ^ ((row&7)<<4)));
      }
      #pragma unroll
      for (int di=0;di<4;di++){
        int d = di*16 + lr;
        int byte = ki*64 + lg*16;
        vbf[di] = *(const bf16x8*)(Vcur + d*128 + (byte ^ ((d&7)<<4)));
      }
      __builtin_amdgcn_s_setprio(1);
      #pragma unroll
      for (int di=0;di<4;di++)
        of[di] = __builtin_amdgcn_mfma_f32_16x16x32_bf16(pa, vbf[di], of[di], 0, 0, 0);
      __builtin_amdgcn_s_setprio(0);
    }

    if (pre){
      #pragma unroll
      for (int j=0;j<8;j++)
        *(__bf16*)(Vnxt + (c0v+j)*128 + ((2*rv) ^ (j<<4))) = nv[j];
    }
  }

  {
    float sum = lsum;
    sum += __shfl_xor(sum,16); sum += __shfl_xor(sum,32);
    lsum = sum;
  }
  const int b = bh / 12;
  #pragma unroll
  for (int r=0;r<4;r++){
    float inv = 1.f / __shfl(lsum, lg*4 + r);
    int row = q0 + lg*4 + r;
    size_t base = ((size_t)(b*2048) + row)*768 + h*64;
    #pragma unroll
    for (int di=0;di<4;di++)
      O[base + di*16 + lr] = f2b(of[di][r]*inv);
  }
}

// ---------------- output projection GEMM ----------------
// (R12/R15 verbatim — green) BM=64, BN=64, BK=64: grid 1536 blocks.
__global__ __launch_bounds__(256) void proj_gemm(
    const unsigned short* __restrict__ A,
    const unsigned short* __restrict__ W,
    const float* __restrict__ bias,
    float* __restrict__ out)
{
  __shared__ char smem[16384];
  char* Alds = smem;            // [64][64]
  char* Blds = smem + 8192;     // [64][64]

  const int tid = threadIdx.x;
  const int l = tid & 63, w = tid >> 6;
  const int lr = l & 15, lg = l >> 4;
  const int tm = blockIdx.x % 128;
  const int tn = blockIdx.x / 128;   // 0..11
  const int m0 = tm * 64, n0 = tn * 64;

  f32x4 acc[4];
  #pragma unroll
  for (int j=0;j<4;j++) acc[j] = (f32x4){0.f,0.f,0.f,0.f};

  for (int kt = 0; kt < 12; ++kt){
    const int k0 = kt * 64;
    __syncthreads();
    #pragma unroll
    for (int c = 0; c < 2; ++c){
      int chunk = c*256 + tid;           // 0..511
      int row = chunk >> 3;
      int scc = (chunk & 7) ^ (row & 7);
      __builtin_amdgcn_global_load_lds((GLBU*)(A + (size_t)(m0+row)*768 + k0 + scc*8),
                                       (LDSU*)(Alds + (c*256 + w*64)*16), 16, 0, 0);
      __builtin_amdgcn_global_load_lds((GLBU*)(W + (size_t)(n0+row)*768 + k0 + scc*8),
                                       (LDSU*)(Blds + (c*256 + w*64)*16), 16, 0, 0);
    }
    __syncthreads();
    #pragma unroll
    for (int kk = 0; kk < 2; ++kk){
      bf16x8 af, bfv[4];
      {
        int row = w*16 + lr;
        int byte = kk*64 + lg*16;
        af = *(const bf16x8*)(Alds + row*128 + (byte ^ ((row&7)<<4)));
      }
      #pragma unroll
      for (int n=0;n<4;n++){
        int row = n*16 + lr;
        int byte = kk*64 + lg*16;
        bfv[n] = *(const bf16x8*)(Blds + row*128 + (byte ^ ((row&7)<<4)));
      }
      #pragma unroll
      for (int n=0;n<4;n++)
        acc[n] = __builtin_amdgcn_mfma_f32_16x16x32_bf16(af, bfv[n], acc[n], 0, 0, 0);
    }
  }

  #pragma unroll
  for (int r=0;r<4;r++){
    int grow = m0 + w*16 + lg*4 + r;
    #pragma unroll
    for (int n=0;n<4;n++){
      int colg = n0 + n*16 + lr;
      out[(size_t)grow*768 + colg] = acc[n][r] + bias[colg];
    }
  }
}

extern "C" void kernel_launch(void* const* d_in, const int* in_sizes, int n_in,
                              void* d_out, int out_size, void* d_ws, size_t ws_size,
                              hipStream_t stream)
{
  const float* x     = (const float*)d_in[0];
  // d_in[1] = attn_bias: implemented implicitly (block-causal, BLOCK=128)
  const float* Wqkv  = (const float*)d_in[2];
  const float* qbias = (const float*)d_in[3];
  const float* vbias = (const float*)d_in[4];
  const float* lsm   = (const float*)d_in[5];
  const float* Wproj = (const float*)d_in[6];
  const float* bproj = (const float*)d_in[7];
  float* out = (float*)d_out;

  char* ws = (char*)d_ws;
  size_t off = 0;
  auto alloc = [&](size_t bytes)->char*{
    char* p = ws + off; off += (bytes + 255) & ~(size_t)255; return p;
  };
  unsigned short* xb  = (unsigned short*)alloc((size_t)8192*768*2);
  unsigned short* wqb = (unsigned short*)alloc((size_t)2304*768*2);
  unsigned short* wpb = (unsigned short*)alloc((size_t)768*768*2);
  unsigned short* qn  = (unsigned short*)alloc((size_t)48*2048*64*2);
  unsigned short* kn  = (unsigned short*)alloc((size_t)48*2048*64*2);
  unsigned short* vn  = (unsigned short*)alloc((size_t)48*2048*64*2);
  unsigned short* ob  = (unsigned short*)alloc((size_t)8192*768*2);

  // fused convert: 1572864 + 442368 + 147456 float4 chunks = 2162688 threads
  cvt3_kernel<<<8448, 256, 0, stream>>>((const float4*)x,     (ushort4*)xb,  1572864,
                                        (const float4*)Wqkv,  (ushort4*)wqb,  442368,
                                        (const float4*)Wproj, (ushort4*)wpb,  147456);
  qkv_gemm<<<64*18, 512, 0, stream>>>(xb, wqb, qbias, vbias, lsm, qn, kn, vn);
  attn_kernel<<<768, 512, 0, stream>>>(qn, kn, vn, lsm, ob);
  proj_gemm<<<128*12, 256, 0, stream>>>(ob, wpb, bproj, out);
}

// Round 19
// 119.305 us; speedup vs baseline: 1.0769x; 1.0769x over previous
//
#include <hip/hip_runtime.h>
#include <hip/hip_bf16.h>

#define DEV __device__ __forceinline__

typedef __bf16 bf16x8 __attribute__((ext_vector_type(8)));
typedef float  f32x4  __attribute__((ext_vector_type(4)));

typedef __attribute__((address_space(3))) unsigned int LDSU;
typedef __attribute__((address_space(1))) const unsigned int GLBU;

DEV unsigned short f2b(float f){
  __bf16 h = (__bf16)f;
  return __builtin_bit_cast(unsigned short, h);
}

static constexpr float MAXLOG = 4.60517018598809136804f;  // log(100)
static constexpr float L2E    = 1.44269504088896340736f;  // log2(e)

// ---------------- fused fp32 -> bf16 convert: x | W_qkv | W_proj ----------------
DEV ushort4 cvt4(float4 v){
  ushort4 o; o.x = f2b(v.x); o.y = f2b(v.y); o.z = f2b(v.z); o.w = f2b(v.w); return o;
}
__global__ void cvt3_kernel(const float4* __restrict__ a, ushort4* __restrict__ da, int na,
                            const float4* __restrict__ b, ushort4* __restrict__ db, int nb,
                            const float4* __restrict__ c, ushort4* __restrict__ dc, int nc){
  int i = blockIdx.x * 256 + threadIdx.x;
  if (i < na) { da[i] = cvt4(a[i]); return; }
  i -= na;
  if (i < nb) { db[i] = cvt4(b[i]); return; }
  i -= nb;
  if (i < nc) { dc[i] = cvt4(c[i]); }
}

// ---------------- QKV GEMM + bias + L2norm/scale epilogue ----------------
// (R18 verbatim — green) BM=128, BN=128, BK=64, 512 thr / 8 waves, dbuf.
// q additionally scaled by log2(e) so attn can use raw v_exp_f32 (2^x).
__global__ __launch_bounds__(512) void qkv_gemm(
    const unsigned short* __restrict__ X,
    const unsigned short* __restrict__ W,
    const float* __restrict__ qbias, const float* __restrict__ vbias,
    const float* __restrict__ lsm,
    unsigned short* __restrict__ Qo, unsigned short* __restrict__ Ko,
    unsigned short* __restrict__ Vo)
{
  __shared__ char smem[65536];   // A dbuf 2x16K @0 | B dbuf 2x16K @32768
  const int tid = threadIdx.x;
  const int l = tid & 63, w = tid >> 6;   // 8 waves
  const int wr = w >> 1, wc = w & 1;      // 4 x 2 wave grid
  const int lr = l & 15, lg = l >> 4;
  const int tm = blockIdx.x % 64;
  const int tn = blockIdx.x / 64;         // 0..17
  const int m0 = tm * 128, n0 = tn * 128;

  f32x4 acc[2][4];
  #pragma unroll
  for (int i=0;i<2;i++)
    #pragma unroll
    for (int j=0;j<4;j++) acc[i][j] = (f32x4){0.f,0.f,0.f,0.f};

  #pragma unroll
  for (int c=0;c<2;++c){
    int chunk = c*512 + tid;
    int row = chunk >> 3;
    int scc = (chunk & 7) ^ (row & 7);    // inverse-swizzled source chunk
    __builtin_amdgcn_global_load_lds((GLBU*)(X + (size_t)(m0+row)*768 + scc*8),
                                     (LDSU*)(smem + chunk*16), 16, 0, 0);
    __builtin_amdgcn_global_load_lds((GLBU*)(W + (size_t)(n0+row)*768 + scc*8),
                                     (LDSU*)(smem + 32768 + chunk*16), 16, 0, 0);
  }

  for (int kt = 0; kt < 12; ++kt){
    __syncthreads();                      // parity (kt&1) staged & visible
    const int pc = kt & 1;
    char* Acur = smem + pc*16384;
    char* Bcur = smem + 32768 + pc*16384;

    if (kt + 1 < 12){                     // stage-early next K-tile (no waits)
      const int k1 = (kt+1)*64;
      char* Anxt = smem + (pc^1)*16384;
      char* Bnxt = smem + 32768 + (pc^1)*16384;
      #pragma unroll
      for (int c=0;c<2;++c){
        int chunk = c*512 + tid;
        int row = chunk >> 3;
        int scc = (chunk & 7) ^ (row & 7);
        __builtin_amdgcn_global_load_lds((GLBU*)(X + (size_t)(m0+row)*768 + k1 + scc*8),
                                         (LDSU*)(Anxt + chunk*16), 16, 0, 0);
        __builtin_amdgcn_global_load_lds((GLBU*)(W + (size_t)(n0+row)*768 + k1 + scc*8),
                                         (LDSU*)(Bnxt + chunk*16), 16, 0, 0);
      }
    }

    #pragma unroll
    for (int kk = 0; kk < 2; ++kk){
      bf16x8 af[2], bfv[4];
      #pragma unroll
      for (int m=0;m<2;m++){
        int row = wr*32 + m*16 + lr;
        int byte = kk*64 + lg*16;
        af[m] = *(const bf16x8*)(Acur + row*128 + (byte ^ ((row&7)<<4)));
      }
      #pragma unroll
      for (int n=0;n<4;n++){
        int row = wc*64 + n*16 + lr;
        int byte = kk*64 + lg*16;
        bfv[n] = *(const bf16x8*)(Bcur + row*128 + (byte ^ ((row&7)<<4)));
      }
      #pragma unroll
      for (int m=0;m<2;m++)
        #pragma unroll
        for (int n=0;n<4;n++)
          acc[m][n] = __builtin_amdgcn_mfma_f32_16x16x32_bf16(af[m], bfv[n], acc[m][n], 0, 0, 0);
    }
  }

  const int nb = n0 + wc*64;
  const int seg = nb / 768;             // 0=q, 1=k, 2=v
  const int h = (nb % 768) / 64;
  float mul = 1.0f;
  if (seg == 0) mul = __expf(fminf(lsm[h], MAXLOG)) * L2E;   // fold log2e into q
  float bias_v[4];
  #pragma unroll
  for (int n=0;n<4;n++){
    int d = n*16 + lr;
    bias_v[n] = (seg==0) ? qbias[h*64+d] : (seg==2 ? vbias[h*64+d] : 0.f);
  }
  unsigned short* dst = (seg==0) ? Qo : (seg==1 ? Ko : Vo);
  #pragma unroll
  for (int m=0;m<2;m++){
    #pragma unroll
    for (int r=0;r<4;r++){
      float vals[4]; float ss = 0.f;
      #pragma unroll
      for (int n=0;n<4;n++){ float v = acc[m][n][r] + bias_v[n]; vals[n] = v; ss += v*v; }
      ss += __shfl_xor(ss,1); ss += __shfl_xor(ss,2);
      ss += __shfl_xor(ss,4); ss += __shfl_xor(ss,8);
      float sc = (seg==2) ? 1.f : mul / fmaxf(sqrtf(ss), 1e-12f);
      int grow = m0 + wr*32 + m*16 + lg*4 + r;   // 0..8191
      int b = grow >> 11, lrow = grow & 2047;
      size_t base = (((size_t)(b*12 + h))*2048 + lrow)*64;
      #pragma unroll
      for (int n=0;n<4;n++) dst[base + n*16 + lr] = f2b(vals[n]*sc);
    }
  }
}

// ---------------- block-causal flash attention (8 waves, 16 q-rows/wave) ----------------
// (R18 structure). CHANGE vs R18: exp2f (libm, slow) -> __builtin_amdgcn_exp2f
// (raw v_exp_f32). With q pre-scaled by log2e this is exact softmax with one
// v_exp and zero muls per P value.
__global__ __launch_bounds__(512) void attn_kernel(
    const unsigned short* __restrict__ Q,
    const unsigned short* __restrict__ K,
    const unsigned short* __restrict__ V,
    const float* __restrict__ lsm,
    unsigned short* __restrict__ O)
{
  __shared__ char smem[49152];     // K dbuf 16K | V dbuf 16K | P 8x2K
  const int tid = threadIdx.x;
  const int l = tid & 63, w = tid >> 6;          // 8 waves
  char* Plds = smem + 32768 + w*2048;            // per-wave [16 q][64 key] bf16, swizzled
  const int lr = l & 15, lg = l >> 4;

  const int bid = blockIdx.x;
  const int qb = 15 - (bid / 48);        // heaviest q-blocks first (LPT)
  const int bh = bid % 48;
  const int h = bh % 12;
  const size_t plane = (size_t)bh * (2048*64);
  const int q0 = qb*128 + w*16;          // 16 q-rows per wave

  // fixed softmax shift in log2 domain (q carries log2e: S = L2E * smul * cos)
  const float M = __expf(fminf(lsm[h], MAXLOG)) * L2E;

  bf16x8 qf[2];
  #pragma unroll
  for (int ki=0;ki<2;ki++)
    qf[ki] = *(const bf16x8*)(Q + plane + (size_t)(q0 + lr)*64 + ki*32 + lg*8);

  float lsum = 0.f;
  f32x4 of[4];
  #pragma unroll
  for (int di=0;di<4;di++) of[di] = (f32x4){0.f,0.f,0.f,0.f};

  const int krow = tid >> 3;                 // 0..63
  const int kscc = (tid & 7) ^ (krow & 7);   // K inverse-swizzled source chunk
  const int rv  = tid & 63;                  // V row (per-wave: all 64 rows)
  const int c0v = (tid >> 6) * 8;            // V d-chunk (per-wave constant)

  const int nt = (qb + 1) * 2;     // visible 64-key tiles (block-causal, BLOCK=128)

  {
    const unsigned short* Kt0 = K + plane;
    const unsigned short* Vt0 = V + plane;
    __builtin_amdgcn_global_load_lds((GLBU*)(Kt0 + krow*64 + kscc*8),
                                     (LDSU*)(smem + tid*16), 16, 0, 0);
    bf16x8 a = *(const bf16x8*)(Vt0 + rv*64 + c0v);
    #pragma unroll
    for (int j=0;j<8;j++)
      *(__bf16*)(smem + 16384 + (c0v+j)*128 + ((2*rv) ^ (j<<4))) = a[j];
  }

  for (int t = 0; t < nt; ++t){
    __syncthreads();
    const int pc = t & 1;
    char* Kcur = smem + pc*8192;
    char* Vcur = smem + 16384 + pc*8192;
    char* Knxt = smem + (pc^1)*8192;
    char* Vnxt = smem + 16384 + (pc^1)*8192;
    const bool pre = (t+1) < nt;

    bf16x8 nv;
    if (pre){
      const unsigned short* Kt1 = K + plane + (size_t)(t+1)*4096;
      const unsigned short* Vt1 = V + plane + (size_t)(t+1)*4096;
      __builtin_amdgcn_global_load_lds((GLBU*)(Kt1 + krow*64 + kscc*8),
                                       (LDSU*)(Knxt + tid*16), 16, 0, 0);
      nv = *(const bf16x8*)(Vt1 + rv*64 + c0v);
    }

    f32x4 s[4];
    #pragma unroll
    for (int ni=0;ni<4;ni++) s[ni] = (f32x4){0.f,0.f,0.f,0.f};
    #pragma unroll
    for (int ki=0;ki<2;ki++){
      bf16x8 kb[4];
      #pragma unroll
      for (int ni=0;ni<4;ni++){
        int key = ni*16 + lr;
        int byte = ki*64 + lg*16;
        kb[ni] = *(const bf16x8*)(Kcur + key*128 + (byte ^ ((key&7)<<4)));
      }
      __builtin_amdgcn_s_setprio(1);
      #pragma unroll
      for (int ni=0;ni<4;ni++)
        s[ni] = __builtin_amdgcn_mfma_f32_16x16x32_bf16(kb[ni], qf[ki], s[ni], 0, 0, 0);
      __builtin_amdgcn_s_setprio(0);
    }

    // fixed-max softmax: P = 2^(s - M) via raw v_exp_f32; u32-pair packed stores
    {
      const int row = lr;
      float a16 = 0.f;
      #pragma unroll
      for (int ni=0;ni<4;ni++){
        float p0 = __builtin_amdgcn_exp2f(s[ni][0] - M);
        float p1 = __builtin_amdgcn_exp2f(s[ni][1] - M);
        float p2 = __builtin_amdgcn_exp2f(s[ni][2] - M);
        float p3 = __builtin_amdgcn_exp2f(s[ni][3] - M);
        a16 += (p0 + p1) + (p2 + p3);
        uint2 uv;
        uv.x = (unsigned)f2b(p0) | ((unsigned)f2b(p1) << 16);
        uv.y = (unsigned)f2b(p2) | ((unsigned)f2b(p3) << 16);
        *(uint2*)(Plds + row*128 + ((ni*32 + lg*8) ^ ((row&7)<<4))) = uv;
      }
      lsum += a16;
    }
    asm volatile("s_waitcnt lgkmcnt(0)" ::: "memory");
    __builtin_amdgcn_sched_barrier(0);

    #pragma unroll
    for (int ki=0;ki<2;ki++){
      bf16x8 pa, vbf[4];
      {
        int row = lr;
        int byte = ki*64 + lg*16;
        pa = *(const bf16x8*)(Plds + row*128 + (byte ^ ((row&7)<<4)));
      }
      #pragma unroll
      for (int di=0;di<4;di++){
        int d = di*16 + lr;
        int byte = ki*64 + lg*16;
        vbf[di] = *(const bf16x8*)(Vcur + d*128 + (byte ^ ((d&7)<<4)));
      }
      __builtin_amdgcn_s_setprio(1);
      #pragma unroll
      for (int di=0;di<4;di++)
        of[di] = __builtin_amdgcn_mfma_f32_16x16x32_bf16(pa, vbf[di], of[di], 0, 0, 0);
      __builtin_amdgcn_s_setprio(0);
    }

    if (pre){
      #pragma unroll
      for (int j=0;j<8;j++)
        *(__bf16*)(Vnxt + (c0v+j)*128 + ((2*rv) ^ (j<<4))) = nv[j];
    }
  }

  {
    float sum = lsum;
    sum += __shfl_xor(sum,16); sum += __shfl_xor(sum,32);
    lsum = sum;
  }
  const int b = bh / 12;
  #pragma unroll
  for (int r=0;r<4;r++){
    float inv = 1.f / __shfl(lsum, lg*4 + r);
    int row = q0 + lg*4 + r;
    size_t base = ((size_t)(b*2048) + row)*768 + h*64;
    #pragma unroll
    for (int di=0;di<4;di++)
      O[base + di*16 + lr] = f2b(of[di][r]*inv);
  }
}

// ---------------- output projection GEMM ----------------
// (R12/R15 verbatim — green) BM=64, BN=64, BK=64: grid 1536 blocks.
__global__ __launch_bounds__(256) void proj_gemm(
    const unsigned short* __restrict__ A,
    const unsigned short* __restrict__ W,
    const float* __restrict__ bias,
    float* __restrict__ out)
{
  __shared__ char smem[16384];
  char* Alds = smem;            // [64][64]
  char* Blds = smem + 8192;     // [64][64]

  const int tid = threadIdx.x;
  const int l = tid & 63, w = tid >> 6;
  const int lr = l & 15, lg = l >> 4;
  const int tm = blockIdx.x % 128;
  const int tn = blockIdx.x / 128;   // 0..11
  const int m0 = tm * 64, n0 = tn * 64;

  f32x4 acc[4];
  #pragma unroll
  for (int j=0;j<4;j++) acc[j] = (f32x4){0.f,0.f,0.f,0.f};

  for (int kt = 0; kt < 12; ++kt){
    const int k0 = kt * 64;
    __syncthreads();
    #pragma unroll
    for (int c = 0; c < 2; ++c){
      int chunk = c*256 + tid;           // 0..511
      int row = chunk >> 3;
      int scc = (chunk & 7) ^ (row & 7);
      __builtin_amdgcn_global_load_lds((GLBU*)(A + (size_t)(m0+row)*768 + k0 + scc*8),
                                       (LDSU*)(Alds + (c*256 + w*64)*16), 16, 0, 0);
      __builtin_amdgcn_global_load_lds((GLBU*)(W + (size_t)(n0+row)*768 + k0 + scc*8),
                                       (LDSU*)(Blds + (c*256 + w*64)*16), 16, 0, 0);
    }
    __syncthreads();
    #pragma unroll
    for (int kk = 0; kk < 2; ++kk){
      bf16x8 af, bfv[4];
      {
        int row = w*16 + lr;
        int byte = kk*64 + lg*16;
        af = *(const bf16x8*)(Alds + row*128 + (byte ^ ((row&7)<<4)));
      }
      #pragma unroll
      for (int n=0;n<4;n++){
        int row = n*16 + lr;
        int byte = kk*64 + lg*16;
        bfv[n] = *(const bf16x8*)(Blds + row*128 + (byte ^ ((row&7)<<4)));
      }
      #pragma unroll
      for (int n=0;n<4;n++)
        acc[n] = __builtin_amdgcn_mfma_f32_16x16x32_bf16(af, bfv[n], acc[n], 0, 0, 0);
    }
  }

  #pragma unroll
  for (int r=0;r<4;r++){
    int grow = m0 + w*16 + lg*4 + r;
    #pragma unroll
    for (int n=0;n<4;n++){
      int colg = n0 + n*16 + lr;
      out[(size_t)grow*768 + colg] = acc[n][r] + bias[colg];
    }
  }
}

extern "C" void kernel_launch(void* const* d_in, const int* in_sizes, int n_in,
                              void* d_out, int out_size, void* d_ws, size_t ws_size,
                              hipStream_t stream)
{
  const float* x     = (const float*)d_in[0];
  // d_in[1] = attn_bias: implemented implicitly (block-causal, BLOCK=128)
  const float* Wqkv  = (const float*)d_in[2];
  const float* qbias = (const float*)d_in[3];
  const float* vbias = (const float*)d_in[4];
  const float* lsm   = (const float*)d_in[5];
  const float* Wproj = (const float*)d_in[6];
  const float* bproj = (const float*)d_in[7];
  float* out = (float*)d_out;

  char* ws = (char*)d_ws;
  size_t off = 0;
  auto alloc = [&](size_t bytes)->char*{
    char* p = ws + off; off += (bytes + 255) & ~(size_t)255; return p;
  };
  unsigned short* xb  = (unsigned short*)alloc((size_t)8192*768*2);
  unsigned short* wqb = (unsigned short*)alloc((size_t)2304*768*2);
  unsigned short* wpb = (unsigned short*)alloc((size_t)768*768*2);
  unsigned short* qn  = (unsigned short*)alloc((size_t)48*2048*64*2);
  unsigned short* kn  = (unsigned short*)alloc((size_t)48*2048*64*2);
  unsigned short* vn  = (unsigned short*)alloc((size_t)48*2048*64*2);
  unsigned short* ob  = (unsigned short*)alloc((size_t)8192*768*2);

  // fused convert: 1572864 + 442368 + 147456 float4 chunks = 2162688 threads
  cvt3_kernel<<<8448, 256, 0, stream>>>((const float4*)x,     (ushort4*)xb,  1572864,
                                        (const float4*)Wqkv,  (ushort4*)wqb,  442368,
                                        (const float4*)Wproj, (ushort4*)wpb,  147456);
  qkv_gemm<<<64*18, 512, 0, stream>>>(xb, wqb, qbias, vbias, lsm, qn, kn, vn);
  attn_kernel<<<768, 512, 0, stream>>>(qn, kn, vn, lsm, ob);
  proj_gemm<<<128*12, 256, 0, stream>>>(ob, wpb, bproj, out);
}